// Round 12
// baseline (2477.546 us; speedup 1.0000x reference)
//
#include <hip/hip_runtime.h>
#include <math.h>

#define VOCAB 50257
#define VPAD  50432
#define DM    1024
#define NH    16
#define DKH   64
#define FF    4096
#define NL    4
#define SEQ   2048
#define BATCH 2
#define MROWS (BATCH*SEQ)

typedef __bf16 bf16_t;
typedef __bf16 bf16x8 __attribute__((ext_vector_type(8)));
typedef __bf16 bf16x4 __attribute__((ext_vector_type(4)));
typedef float  f32x4  __attribute__((ext_vector_type(4)));

typedef void as1_void __attribute__((address_space(1)));
typedef void as3_void __attribute__((address_space(3)));

__device__ __forceinline__ void gload_lds16(const void* g, void* l) {
  __builtin_amdgcn_global_load_lds((as1_void*)g, (as3_void*)l, 16, 0, 0);
}

__device__ __forceinline__ uint32_t lds_addr32(const void* p) {
  return (uint32_t)(uintptr_t)(as3_void*)p;
}

// compiler-invisible LDS read (R4: breaks backend's conservative vmcnt drains)
__device__ __forceinline__ bf16x8 dsr128(uint32_t addr) {
  bf16x8 v;
  asm volatile("ds_read_b128 %0, %1" : "=v"(v) : "v"(addr));
  return v;
}

#define FENCE asm volatile("" ::: "memory")
#define BAR() do { FENCE; __builtin_amdgcn_s_barrier(); FENCE; } while (0)
#define LGKM0_FENCE() do { \
  asm volatile("s_waitcnt lgkmcnt(0)" ::: "memory"); \
  __builtin_amdgcn_sched_barrier(0); \
} while (0)

// ---------------- embedding + positional encoding ----------------
__global__ __launch_bounds__(256) void embed_kernel(const int* __restrict__ x,
    const float* __restrict__ emb, float* __restrict__ h) {
  int row = blockIdx.x;
  int s = row & (SEQ - 1);
  int d = threadIdx.x * 4;
  const float* e = emb + (size_t)x[row] * DM + d;
  float4 v = *(const float4*)e;
  float vin[4] = {v.x, v.y, v.z, v.w};
  float out[4];
#pragma unroll
  for (int j = 0; j < 4; ++j) {
    int dd = d + j;
    int i = dd >> 1;
    float freq = expf(-0.017988946039016376f * (float)i);
    float ang = (float)s * freq;
    float pe = (dd & 1) ? cosf(ang) : sinf(ang);
    out[j] = vin[j] + pe;
  }
  *(float4*)(h + (size_t)row * DM + d) = make_float4(out[0], out[1], out[2], out[3]);
}

// ---------------- layernorm (f32 in -> bf16 out) ----------------
__global__ __launch_bounds__(256) void ln_kernel(const float* __restrict__ x,
    const float* __restrict__ g, const float* __restrict__ b, bf16_t* __restrict__ out) {
  int row = blockIdx.x;
  int tid = threadIdx.x, lane = tid & 63, wave = tid >> 6;
  const float* xr = x + (size_t)row * DM;
  float4 v = ((const float4*)xr)[tid];
  float s1 = v.x + v.y + v.z + v.w;
  float s2 = v.x * v.x + v.y * v.y + v.z * v.z + v.w * v.w;
#pragma unroll
  for (int d = 1; d < 64; d <<= 1) { s1 += __shfl_xor(s1, d); s2 += __shfl_xor(s2, d); }
  __shared__ float red[8];
  if (lane == 0) { red[wave] = s1; red[4 + wave] = s2; }
  __syncthreads();
  s1 = red[0] + red[1] + red[2] + red[3];
  s2 = red[4] + red[5] + red[6] + red[7];
  float mu = s1 * (1.0f / DM);
  float var = s2 * (1.0f / DM) - mu * mu;
  float rs = rsqrtf(var + 1e-5f);
  float4 gv = ((const float4*)g)[tid];
  float4 bv = ((const float4*)b)[tid];
  bf16x4 o;
  o[0] = (bf16_t)((v.x - mu) * rs * gv.x + bv.x);
  o[1] = (bf16_t)((v.y - mu) * rs * gv.y + bv.y);
  o[2] = (bf16_t)((v.z - mu) * rs * gv.z + bv.z);
  o[3] = (bf16_t)((v.w - mu) * rs * gv.w + bv.w);
  *(bf16x4*)(out + (size_t)row * DM + tid * 4) = o;
}

// ------------- transpose + cast: f32 [K][N] -> bf16 [Npad][K] (head only) -------------
__global__ __launch_bounds__(256) void transpose_cast_kernel(const float* __restrict__ in,
    bf16_t* __restrict__ out, int K, int N, int Npad) {
  __shared__ float tile[32][33];
  int n0 = blockIdx.x * 32, k0 = blockIdx.y * 32;
  int tx = threadIdx.x & 31, ty = threadIdx.x >> 5;
#pragma unroll
  for (int kk = ty; kk < 32; kk += 8) {
    int n = n0 + tx;
    tile[kk][tx] = (n < N) ? in[(size_t)(k0 + kk) * N + n] : 0.f;
  }
  __syncthreads();
#pragma unroll
  for (int nn = ty; nn < 32; nn += 8) {
    out[(size_t)(n0 + nn) * K + k0 + tx] = (bf16_t)tile[tx][nn];
  }
}

// ------------- fused per-layer weight transpose (one launch) -------------
__global__ __launch_bounds__(256) void wtrans_kernel(
    const float* __restrict__ wq, const float* __restrict__ wk,
    const float* __restrict__ wv, const float* __restrict__ wo,
    const float* __restrict__ w1, const float* __restrict__ w2,
    bf16_t* __restrict__ qkvT, bf16_t* __restrict__ woT,
    bf16_t* __restrict__ w1T, bf16_t* __restrict__ w2T) {
  int id = blockIdx.x;
  const float* src; bf16_t* dst; int K, N, tk, tn;
  if (id < 4096) {
    int m = id >> 10, tile_i = id & 1023;
    tk = tile_i >> 5; tn = tile_i & 31; K = 1024; N = 1024;
    src = (m == 0) ? wq : (m == 1) ? wk : (m == 2) ? wv : wo;
    dst = (m < 3) ? qkvT + (size_t)m * DM * DM : woT;
  } else if (id < 8192) {
    int tile_i = id - 4096;
    tk = tile_i >> 7; tn = tile_i & 127; K = 1024; N = 4096;
    src = w1; dst = w1T;
  } else {
    int tile_i = id - 8192;
    tk = tile_i >> 5; tn = tile_i & 31; K = 4096; N = 1024;
    src = w2; dst = w2T;
  }
  __shared__ float tile[32][33];
  int n0 = tn * 32, k0 = tk * 32;
  int tx = threadIdx.x & 31, ty = threadIdx.x >> 5;
#pragma unroll
  for (int kk = ty; kk < 32; kk += 8)
    tile[kk][tx] = src[(size_t)(k0 + kk) * N + n0 + tx];
  __syncthreads();
#pragma unroll
  for (int nn = ty; nn < 32; nn += 8)
    dst[(size_t)(n0 + nn) * K + k0 + tx] = (bf16_t)tile[tx][nn];
}

// ------------- V transpose: qkv V slice -> vT [b][h][dk][S] (bf16) -------------
__global__ __launch_bounds__(256) void vtrans_kernel(const bf16_t* __restrict__ qkv,
    bf16_t* __restrict__ vT) {
  int sb = blockIdx.x, hh = blockIdx.y, bb = blockIdx.z;
  __shared__ bf16_t t[64][72];   // +8 pad
  int tid = threadIdx.x;
  const bf16_t* src = qkv + ((size_t)bb * SEQ + sb * 64) * (3 * DM) + 2 * DM + hh * DKH;
#pragma unroll
  for (int c = 0; c < 2; ++c) {
    int u = c * 256 + tid;
    int s = u >> 3, d8 = u & 7;
    *(bf16x8*)&t[s][d8 * 8] = *(const bf16x8*)(src + (size_t)s * (3 * DM) + d8 * 8);
  }
  __syncthreads();
  bf16_t* dst = vT + ((size_t)(bb * NH + hh) * DKH) * SEQ + sb * 64;
#pragma unroll
  for (int c = 0; c < 2; ++c) {
    int u = c * 256 + tid;
    int dk = u >> 3, s8 = u & 7;
    bf16x8 v;
#pragma unroll
    for (int j = 0; j < 8; ++j) v[j] = t[s8 * 8 + j][dk];
    *(bf16x8*)(dst + (size_t)dk * SEQ + s8 * 8) = v;
  }
}

// ---------------- gemm128-BK64: asm-dsr pipeline, 64 KB LDS dbuf (qkv/wo/ffn1/w2) ----------------
__global__ __launch_bounds__(256, 2) void gemm128_kernel(
    const bf16_t* __restrict__ A, const bf16_t* __restrict__ Bt, int K,
    const float* __restrict__ bias, const float* __restrict__ Rsd,
    float* Cf, bf16_t* Cb, int ldc, int Nvalid, int relu, int gridM, int gridN) {
  __shared__ __align__(16) bf16_t lds[32768];   // 64 KB

  int nwg = gridM * gridN;
  int orig = blockIdx.x;
  int q = nwg >> 3, rr = nwg & 7;
  int xcd = orig & 7, idx = orig >> 3;
  int swz = (xcd < rr ? xcd * (q + 1) : rr * (q + 1) + (xcd - rr) * q) + idx;
  int bm = swz % gridM, bn = swz / gridM;
  int m0 = bm * 128, n0 = bn * 128;

  int tid = threadIdx.x, lane = tid & 63, wave = tid >> 6;
  int g = lane >> 4, r = lane & 15;
  int wr = wave >> 1, wc = wave & 1;

  f32x4 zero = {0.f, 0.f, 0.f, 0.f};
  f32x4 acc[4][4];
#pragma unroll
  for (int i = 0; i < 4; ++i)
#pragma unroll
    for (int j = 0; j < 4; ++j) acc[i][j] = zero;

  const bf16_t* Abase = A + (size_t)m0 * K;
  const bf16_t* Bbase = Bt + (size_t)n0 * K;
  int NT = K >> 6;

  uint32_t L0 = lds_addr32(lds);
  uint32_t aF = L0 + (uint32_t)((g * 128 + wr * 64 + r) * 16);
  uint32_t bF = L0 + 32768u + (uint32_t)((g * 128 + wc * 64 + r) * 16);

  auto stage = [&](int t) {
    int b = t & 1, k0 = t << 6;
    bf16_t* dA = lds + (size_t)b * 8192;
    bf16_t* dB = lds + 16384 + (size_t)b * 8192;
#pragma unroll
    for (int j = 0; j < 4; ++j) {
      int u = j * 256 + tid;
      int row = u & 127, k8 = u >> 7;
      gload_lds16(Abase + (size_t)row * K + k0 + k8 * 8, dA + (j * 256 + wave * 64) * 8);
    }
#pragma unroll
    for (int j = 0; j < 4; ++j) {
      int u = j * 256 + tid;
      int row = u & 127, k8 = u >> 7;
      gload_lds16(Bbase + (size_t)row * K + k0 + k8 * 8, dB + (j * 256 + wave * 64) * 8);
    }
  };

  stage(0);
  if (NT > 1) {
    stage(1);
    asm volatile("s_waitcnt vmcnt(8)" ::: "memory");
  } else {
    asm volatile("s_waitcnt vmcnt(0)" ::: "memory");
  }
  BAR();

  for (int t = 0; t < NT; ++t) {
    uint32_t boff = (uint32_t)((t & 1) << 14);
    bf16x8 af[4][2], bfr[4][2];
#pragma unroll
    for (int mr = 0; mr < 4; ++mr)
#pragma unroll
      for (int kk = 0; kk < 2; ++kk)
        af[mr][kk] = dsr128(aF + boff + (uint32_t)(kk * 8192 + mr * 256));
#pragma unroll
    for (int nr = 0; nr < 4; ++nr)
#pragma unroll
      for (int kk = 0; kk < 2; ++kk)
        bfr[nr][kk] = dsr128(bF + boff + (uint32_t)(kk * 8192 + nr * 256));
    LGKM0_FENCE();
    BAR();
    if (t + 2 < NT) stage(t + 2);
    __builtin_amdgcn_s_setprio(1);
#pragma unroll
    for (int mr = 0; mr < 4; ++mr)
#pragma unroll
      for (int nr = 0; nr < 4; ++nr) {
        acc[mr][nr] = __builtin_amdgcn_mfma_f32_16x16x32_bf16(af[mr][0], bfr[nr][0], acc[mr][nr], 0, 0, 0);
        acc[mr][nr] = __builtin_amdgcn_mfma_f32_16x16x32_bf16(af[mr][1], bfr[nr][1], acc[mr][nr], 0, 0, 0);
      }
    __builtin_amdgcn_s_setprio(0);
    __builtin_amdgcn_sched_barrier(0);
    if (t + 2 < NT) {
      asm volatile("s_waitcnt vmcnt(8)" ::: "memory");
    } else {
      asm volatile("s_waitcnt vmcnt(0)" ::: "memory");
    }
    BAR();
  }

#pragma unroll
  for (int mr = 0; mr < 4; ++mr) {
    int row = m0 + wr * 64 + mr * 16 + g * 4;
#pragma unroll
    for (int nr = 0; nr < 4; ++nr) {
      int col = n0 + wc * 64 + nr * 16 + r;
      if (col < Nvalid) {
        float bval = bias ? bias[col] : 0.f;
#pragma unroll
        for (int i = 0; i < 4; ++i) {
          float vv = acc[mr][nr][i] + bval;
          if (relu) vv = fmaxf(vv, 0.f);
          size_t idxo = (size_t)(row + i) * ldc + col;
          if (Rsd) vv += Rsd[idxo];
          if (Cf) Cf[idxo] = vv;
          if (Cb) Cb[idxo] = (bf16_t)vv;
        }
      }
    }
  }
}

// ---------------- gemm256: 8-phase, asm ds_reads (head) [R8, best measured] ----------------
__global__ __launch_bounds__(512, 2) void gemm256_kernel(
    const bf16_t* __restrict__ A, const bf16_t* __restrict__ Bt, int K,
    const float* __restrict__ bias, float* Cf, bf16_t* Cb,
    int ldc, int Nvalid, int relu, int gridM, int gridN) {
  __shared__ __align__(16) bf16_t lds[65536];   // 128 KB

  int nwg = gridM * gridN;
  int orig = blockIdx.x;
  int q = nwg >> 3, rr = nwg & 7;
  int xcd = orig & 7, idx = orig >> 3;
  int swz = (xcd < rr ? xcd * (q + 1) : rr * (q + 1) + (xcd - rr) * q) + idx;
  int bm = swz % gridM, bn = swz / gridM;
  int m0 = bm * 256, n0 = bn * 256;

  int tid = threadIdx.x, lane = tid & 63, wave = tid >> 6;
  int g = lane >> 4, r = lane & 15;
  int wr = wave >> 2, wc = wave & 3;   // 2M x 4N

  f32x4 zero = {0.f, 0.f, 0.f, 0.f};
  f32x4 acc[8][4];
#pragma unroll
  for (int i = 0; i < 8; ++i)
#pragma unroll
    for (int j = 0; j < 4; ++j) acc[i][j] = zero;

  const bf16_t* Ab = A + (size_t)m0 * K;
  const bf16_t* Bb = Bt + (size_t)n0 * K;
  int NT = K >> 6;

  uint32_t L0 = lds_addr32(lds);
  uint32_t laneOff = (uint32_t)(g * 2048 + r * 16);
  uint32_t aBase0 = L0 + ((uint32_t)wr << 14) + laneOff;
  uint32_t bBase0 = L0 + 65536u + ((uint32_t)(wc >> 1) << 14) + laneOff
                  + (uint32_t)((wc & 1) * 1024);

  auto stageA = [&](int t, int hh) {
    int b = t & 1, k0 = t << 6;
    const bf16_t* src = Ab + (size_t)(hh * 128) * K + k0;
    bf16_t* dst = lds + (size_t)(b * 2 + hh) * 8192;
#pragma unroll
    for (int j = 0; j < 2; ++j) {
      int u = j * 512 + tid;
      gload_lds16(src + (size_t)(u & 127) * K + (u >> 7) * 8, dst + (j * 512 + wave * 64) * 8);
    }
  };
  auto stageB = [&](int t, int hh) {
    int b = t & 1, k0 = t << 6;
    const bf16_t* src = Bb + (size_t)(hh * 128) * K + k0;
    bf16_t* dst = lds + 32768 + (size_t)(b * 2 + hh) * 8192;
#pragma unroll
    for (int j = 0; j < 2; ++j) {
      int u = j * 512 + tid;
      gload_lds16(src + (size_t)(u & 127) * K + (u >> 7) * 8, dst + (j * 512 + wave * 64) * 8);
    }
  };

  stageB(0, 0); stageB(0, 1); stageA(0, 0); stageA(0, 1);
  if (NT > 1) {
    stageB(1, 0); stageB(1, 1);
    asm volatile("s_waitcnt vmcnt(4)" ::: "memory");
  } else {
    asm volatile("s_waitcnt vmcnt(0)" ::: "memory");
  }
  BAR();

  for (int t = 0; t < NT; ++t) {
    uint32_t bsel = (uint32_t)((t & 1) << 15);
    uint32_t Aaddr = aBase0 + bsel;
    uint32_t Baddr = bBase0 + bsel;

    bf16x8 a0[4][2], a1[4][2], b01[2][2], b23[2][2];

#pragma unroll
    for (int mi = 0; mi < 4; ++mi)
#pragma unroll
      for (int kk = 0; kk < 2; ++kk)
        a0[mi][kk] = dsr128(Aaddr + (uint32_t)(kk * 8192 + mi * 256));
#pragma unroll
    for (int ni = 0; ni < 2; ++ni)
#pragma unroll
      for (int kk = 0; kk < 2; ++kk)
        b01[ni][kk] = dsr128(Baddr + (uint32_t)(kk * 8192 + ni * 256));
    if (t + 1 < NT) stageA(t + 1, 0);
    BAR();
    LGKM0_FENCE();
    __builtin_amdgcn_s_setprio(1);
#pragma unroll
    for (int mi = 0; mi < 4; ++mi)
#pragma unroll
      for (int ni = 0; ni < 2; ++ni)
#pragma unroll
        for (int kk = 0; kk < 2; ++kk)
          acc[mi][ni] = __builtin_amdgcn_mfma_f32_16x16x32_bf16(a0[mi][kk], b01[ni][kk], acc[mi][ni], 0, 0, 0);
    __builtin_amdgcn_s_setprio(0);
    __builtin_amdgcn_sched_barrier(0);
    BAR();

#pragma unroll
    for (int ni = 0; ni < 2; ++ni)
#pragma unroll
      for (int kk = 0; kk < 2; ++kk)
        b23[ni][kk] = dsr128(Baddr + (uint32_t)(kk * 8192 + (ni + 2) * 256));
    if (t + 1 < NT) stageA(t + 1, 1);
    BAR();
    LGKM0_FENCE();
    __builtin_amdgcn_s_setprio(1);
#pragma unroll
    for (int mi = 0; mi < 4; ++mi)
#pragma unroll
      for (int ni = 0; ni < 2; ++ni)
#pragma unroll
        for (int kk = 0; kk < 2; ++kk)
          acc[mi][ni + 2] = __builtin_amdgcn_mfma_f32_16x16x32_bf16(a0[mi][kk], b23[ni][kk], acc[mi][ni + 2], 0, 0, 0);
    __builtin_amdgcn_s_setprio(0);
    __builtin_amdgcn_sched_barrier(0);
    BAR();

#pragma unroll
    for (int mi = 0; mi < 4; ++mi)
#pragma unroll
      for (int kk = 0; kk < 2; ++kk)
        a1[mi][kk] = dsr128(Aaddr + (uint32_t)(kk * 8192 + (mi + 4) * 256));
    if (t + 2 < NT) stageB(t + 2, 0);
    BAR();
    LGKM0_FENCE();
    __builtin_amdgcn_s_setprio(1);
#pragma unroll
    for (int mi = 0; mi < 4; ++mi)
#pragma unroll
      for (int ni = 0; ni < 2; ++ni)
#pragma unroll
        for (int kk = 0; kk < 2; ++kk)
          acc[mi + 4][ni] = __builtin_amdgcn_mfma_f32_16x16x32_bf16(a1[mi][kk], b01[ni][kk], acc[mi + 4][ni], 0, 0, 0);
    __builtin_amdgcn_s_setprio(0);
    __builtin_amdgcn_sched_barrier(0);
    BAR();

    if (t + 2 < NT) stageB(t + 2, 1);
    __builtin_amdgcn_sched_barrier(0);
    __builtin_amdgcn_s_setprio(1);
#pragma unroll
    for (int mi = 0; mi < 4; ++mi)
#pragma unroll
      for (int ni = 0; ni < 2; ++ni)
#pragma unroll
        for (int kk = 0; kk < 2; ++kk)
          acc[mi + 4][ni + 2] = __builtin_amdgcn_mfma_f32_16x16x32_bf16(a1[mi][kk], b23[ni][kk], acc[mi + 4][ni + 2], 0, 0, 0);
    __builtin_amdgcn_s_setprio(0);
    __builtin_amdgcn_sched_barrier(0);
    if (t + 2 < NT) {
      asm volatile("s_waitcnt vmcnt(4)" ::: "memory");
    } else {
      asm volatile("s_waitcnt vmcnt(0)" ::: "memory");
    }
    BAR();
  }

#pragma unroll
  for (int mi = 0; mi < 8; ++mi) {
    int row = m0 + wr * 128 + mi * 16 + g * 4;
#pragma unroll
    for (int ni = 0; ni < 4; ++ni) {
      int col = n0 + wc * 64 + ni * 16 + r;
      if (col < Nvalid) {
        float bval = bias ? bias[col] : 0.f;
#pragma unroll
        for (int i = 0; i < 4; ++i) {
          float vv = acc[mi][ni][i] + bval;
          if (relu) vv = fmaxf(vv, 0.f);
          size_t idxo = (size_t)(row + i) * ldc + col;
          if (Cf) Cf[idxo] = vv;
          if (Cb) Cb[idxo] = (bf16_t)vv;
        }
      }
    }
  }
}

// ---------------- flash attention: async K/V pipeline, QBLK=128, 8 waves [R8] ----------------
__global__ __launch_bounds__(512, 4) void attn_kernel(const bf16_t* __restrict__ Qg,
    const bf16_t* __restrict__ Kg, const bf16_t* __restrict__ vT, bf16_t* __restrict__ Og,
    int ldq) {
  int bq = (int)gridDim.x - 1 - (int)blockIdx.x;
  int hh = blockIdx.y, bb = blockIdx.z;
  int tid = threadIdx.x, lane = tid & 63, wave = tid >> 6;
  int g = lane >> 4, r = lane & 15;
  __shared__ __align__(16) bf16_t Kl[2][4096];
  __shared__ __align__(16) bf16_t Vl[2][4096];
  __shared__ __align__(16) bf16_t Pl[8][1024];

  size_t base = (size_t)bb * SEQ * ldq + hh * DKH;
  size_t vbase = ((size_t)(bb * NH + hh)) * DKH * SEQ;
  size_t baseO = (size_t)bb * SEQ * DM + hh * DKH;
  int q0 = bq * 128 + wave * 16;
  const bf16_t* qrowp = Qg + base + (size_t)(q0 + r) * ldq;
  bf16x8 qf0 = *(const bf16x8*)(qrowp + g * 8);
  bf16x8 qf1 = *(const bf16x8*)(qrowp + 32 + g * 8);
#pragma unroll
  for (int j = 0; j < 8; ++j) {
    qf0[j] = (bf16_t)((float)qf0[j] * 0.125f);
    qf1[j] = (bf16_t)((float)qf1[j] * 0.125f);
  }

  uint32_t KlA = lds_addr32(&Kl[0][0]);
  uint32_t VlA = lds_addr32(&Vl[0][0]);
  int slot0 = g ^ (r & 7), slot1 = (4 + g) ^ (r & 7);

  f32x4 zero = {0.f, 0.f, 0.f, 0.f};
  f32x4 accO[4];
#pragma unroll
  for (int dt = 0; dt < 4; ++dt) accO[dt] = zero;
  float m_i[4], l_i[4];
#pragma unroll
  for (int i = 0; i < 4; ++i) { m_i[i] = -1e30f; l_i[i] = 0.f; }

  int skv = tid >> 3, kslot = tid & 7, kdk8 = kslot ^ (skv & 7);
  int sdk = tid >> 3, vslot = tid & 7, vkv8 = vslot ^ (sdk & 7);
  const bf16_t* ksrc0 = Kg + base + (size_t)skv * ldq + kdk8 * 8;
  const bf16_t* vsrc0 = vT + vbase + (size_t)sdk * SEQ + vkv8 * 8;

  auto stage = [&](int kb) {
    int c = kb & 1;
    gload_lds16(ksrc0 + (size_t)(kb * 64) * ldq, &Kl[c][(wave * 64) * 8]);
    gload_lds16(vsrc0 + kb * 64, &Vl[c][(wave * 64) * 8]);
  };

  int nkb = 2 * bq + 2;
  stage(0); stage(1);
  asm volatile("s_waitcnt vmcnt(2)" ::: "memory");
  BAR();

  for (int kb = 0; kb < nkb; ++kb) {
    uint32_t koff = KlA + (uint32_t)((kb & 1) << 13);
    uint32_t voff = VlA + (uint32_t)((kb & 1) << 13);

    bf16x8 kf[4][2];
#pragma unroll
    for (int ct = 0; ct < 4; ++ct) {
      int kvrow = ct * 16 + r;
      kf[ct][0] = dsr128(koff + (uint32_t)((kvrow * 8 + slot0) * 16));
      kf[ct][1] = dsr128(koff + (uint32_t)((kvrow * 8 + slot1) * 16));
    }
    LGKM0_FENCE();
    f32x4 sc[4];
#pragma unroll
    for (int ct = 0; ct < 4; ++ct) {
      f32x4 s = zero;
      s = __builtin_amdgcn_mfma_f32_16x16x32_bf16(qf0, kf[ct][0], s, 0, 0, 0);
      s = __builtin_amdgcn_mfma_f32_16x16x32_bf16(qf1, kf[ct][1], s, 0, 0, 0);
      sc[ct] = s;
    }

    bool full = (kb * 64 + 63) <= q0;
#pragma unroll
    for (int i = 0; i < 4; ++i) {
      float mx = m_i[i];
      if (full) {
#pragma unroll
        for (int ct = 0; ct < 4; ++ct) mx = fmaxf(mx, sc[ct][i]);
      } else {
        int qglob = q0 + g * 4 + i;
#pragma unroll
        for (int ct = 0; ct < 4; ++ct) {
          int kglob = kb * 64 + ct * 16 + r;
          float s = (kglob <= qglob) ? sc[ct][i] : -1e30f;
          sc[ct][i] = s;
          mx = fmaxf(mx, s);
        }
      }
#pragma unroll
      for (int d = 1; d < 16; d <<= 1) mx = fmaxf(mx, __shfl_xor(mx, d));
      float scl = __expf(m_i[i] - mx);
      l_i[i] *= scl;
      m_i[i] = mx;
      float rsum = 0.f;
#pragma unroll
      for (int ct = 0; ct < 4; ++ct) {
        float p = __expf(sc[ct][i] - mx);
        sc[ct][i] = p;
        rsum += p;
      }
#pragma unroll
      for (int d = 1; d < 16; d <<= 1) rsum += __shfl_xor(rsum, d);
      l_i[i] += rsum;
#pragma unroll
      for (int dt = 0; dt < 4; ++dt) accO[dt][i] *= scl;
    }

#pragma unroll
    for (int ct = 0; ct < 4; ++ct) {
      int kcol = ct * 16 + r;
#pragma unroll
      for (int i = 0; i < 4; ++i)
        Pl[wave][((kcol >> 3) * 16 + g * 4 + i) * 8 + (kcol & 7)] = (bf16_t)sc[ct][i];
    }
    bf16x8 pa0 = *(const bf16x8*)&Pl[wave][((0 + g) * 16 + r) * 8];
    bf16x8 pa1 = *(const bf16x8*)&Pl[wave][((4 + g) * 16 + r) * 8];

    bf16x8 vb[4][2];
#pragma unroll
    for (int dt = 0; dt < 4; ++dt) {
      int dkrow = dt * 16 + r;
      vb[dt][0] = dsr128(voff + (uint32_t)((dkrow * 8 + slot0) * 16));
      vb[dt][1] = dsr128(voff + (uint32_t)((dkrow * 8 + slot1) * 16));
    }
    LGKM0_FENCE();
#pragma unroll
    for (int dt = 0; dt < 4; ++dt) {
      accO[dt] = __builtin_amdgcn_mfma_f32_16x16x32_bf16(pa0, vb[dt][0], accO[dt], 0, 0, 0);
      accO[dt] = __builtin_amdgcn_mfma_f32_16x16x32_bf16(pa1, vb[dt][1], accO[dt], 0, 0, 0);
    }

    BAR();
    if (kb + 2 < nkb) {
      stage(kb + 2);
      asm volatile("s_waitcnt vmcnt(2)" ::: "memory");
    } else {
      asm volatile("s_waitcnt vmcnt(0)" ::: "memory");
    }
    BAR();
  }

#pragma unroll
  for (int dt = 0; dt < 4; ++dt)
#pragma unroll
    for (int i = 0; i < 4; ++i) {
      int rowq = q0 + g * 4 + i;
      Og[baseO + (size_t)rowq * DM + dt * 16 + r] = (bf16_t)(accO[dt][i] / l_i[i]);
    }
}

// ---------------- launcher ----------------
static inline void launch_gemm256(const bf16_t* A, const bf16_t* Bt, int K,
    const float* bias, float* Cf, bf16_t* Cb, int ldc, int Nvalid, int relu,
    int M, int Npad, hipStream_t stream) {
  int gridM = M / 256, gridN = Npad / 256;
  gemm256_kernel<<<dim3(gridM * gridN), 512, 0, stream>>>(
      A, Bt, K, bias, Cf, Cb, ldc, Nvalid, relu, gridM, gridN);
}

static inline void launch_gemm128(const bf16_t* A, const bf16_t* Bt, int K,
    const float* bias, const float* Rsd, float* Cf, bf16_t* Cb,
    int ldc, int Nvalid, int relu, int M, int Npad, hipStream_t stream) {
  int gridM = M / 128, gridN = Npad / 128;
  gemm128_kernel<<<dim3(gridM * gridN), 256, 0, stream>>>(
      A, Bt, K, bias, Rsd, Cf, Cb, ldc, Nvalid, relu, gridM, gridN);
}

extern "C" void kernel_launch(void* const* d_in, const int* in_sizes, int n_in,
                              void* d_out, int out_size, void* d_ws, size_t ws_size,
                              hipStream_t stream) {
  const int*   x      = (const int*)d_in[0];
  const float* emb    = (const float*)d_in[1];
  const float* ln1_g  = (const float*)d_in[2];
  const float* ln1_b  = (const float*)d_in[3];
  const float* wq     = (const float*)d_in[4];
  const float* wk     = (const float*)d_in[5];
  const float* wv     = (const float*)d_in[6];
  const float* wo     = (const float*)d_in[7];
  const float* ln2_g  = (const float*)d_in[8];
  const float* ln2_b  = (const float*)d_in[9];
  const float* w1     = (const float*)d_in[10];
  const float* b1     = (const float*)d_in[11];
  const float* w2     = (const float*)d_in[12];
  const float* b2     = (const float*)d_in[13];
  const float* lnf_g  = (const float*)d_in[14];
  const float* lnf_b  = (const float*)d_in[15];
  const float* head_w = (const float*)d_in[16];
  const float* head_b = (const float*)d_in[17];
  float* out = (float*)d_out;

  char* ws = (char*)d_ws;
  size_t off = 0;
  auto alloc = [&](size_t bytes) -> void* {
    void* p = ws + off;
    off += (bytes + 255) & ~(size_t)255;
    return p;
  };
  float*  h     = (float*)alloc((size_t)MROWS * DM * 4);
  bf16_t* hn    = (bf16_t*)alloc((size_t)MROWS * DM * 2);
  bf16_t* qkv   = (bf16_t*)alloc((size_t)MROWS * 3 * DM * 2);
  bf16_t* atb   = (bf16_t*)alloc((size_t)MROWS * DM * 2);
  bf16_t* ffn1  = (bf16_t*)alloc((size_t)MROWS * FF * 2);
  bf16_t* vTb   = (bf16_t*)alloc((size_t)BATCH * NH * DKH * SEQ * 2);
  bf16_t* headT = (bf16_t*)alloc((size_t)VPAD * DM * 2);
  bf16_t* wqkvT = headT;                                   // 3 x 1M
  bf16_t* woT   = headT + (size_t)3 * DM * DM;             // 1M
  bf16_t* w1T   = headT + (size_t)4 * DM * DM;             // 4M
  bf16_t* w2T   = headT + (size_t)4 * DM * DM + (size_t)DM * FF;  // 4M

  embed_kernel<<<MROWS, 256, 0, stream>>>(x, emb, h);

  for (int l = 0; l < NL; ++l) {
    ln_kernel<<<MROWS, 256, 0, stream>>>(h, ln1_g + l * DM, ln1_b + l * DM, hn);

    wtrans_kernel<<<12288, 256, 0, stream>>>(
        wq + (size_t)l * DM * DM, wk + (size_t)l * DM * DM, wv + (size_t)l * DM * DM,
        wo + (size_t)l * DM * DM, w1 + (size_t)l * DM * FF, w2 + (size_t)l * FF * DM,
        wqkvT, woT, w1T, w2T);

    // qkv: 768 blocks at 2/CU (was 192-block gemm256 at 0.75/CU)
    launch_gemm128(hn, wqkvT, DM, nullptr, nullptr, nullptr, qkv, 3 * DM, 3 * DM, 0,
                   MROWS, 3 * DM, stream);

    vtrans_kernel<<<dim3(SEQ / 64, NH, BATCH), 256, 0, stream>>>(qkv, vTb);
    attn_kernel<<<dim3(SEQ / 128, NH, BATCH), 512, 0, stream>>>(
        qkv, qkv + DM, vTb, atb, 3 * DM);

    launch_gemm128(atb, woT, DM, nullptr, h, h, nullptr, DM, DM, 0, MROWS, DM, stream);

    ln_kernel<<<MROWS, 256, 0, stream>>>(h, ln2_g + l * DM, ln2_b + l * DM, hn);

    // ffn1: 1024 blocks at 2/CU (was 256-block gemm256 at 1/CU)
    launch_gemm128(hn, w1T, DM, b1 + (size_t)l * FF, nullptr, nullptr, ffn1, FF, FF, 1,
                   MROWS, FF, stream);

    launch_gemm128(ffn1, w2T, FF, b2 + (size_t)l * DM, h, h, nullptr, DM, DM, 0,
                   MROWS, DM, stream);
  }

  ln_kernel<<<MROWS, 256, 0, stream>>>(h, lnf_g, lnf_b, hn);
  transpose_cast_kernel<<<dim3(VPAD / 32, DM / 32), 256, 0, stream>>>(
      head_w, headT, DM, VOCAB, VPAD);
  launch_gemm256(hn, headT, DM, head_b, out, nullptr, VOCAB, VOCAB, 0,
                 MROWS, VPAD, stream);
}

// Round 13
// 2258.775 us; speedup vs baseline: 1.0969x; 1.0969x over previous
//
#include <hip/hip_runtime.h>
#include <math.h>

#define VOCAB 50257
#define VPAD  50432
#define DM    1024
#define NH    16
#define DKH   64
#define FF    4096
#define NL    4
#define SEQ   2048
#define BATCH 2
#define MROWS (BATCH*SEQ)

typedef __bf16 bf16_t;
typedef __bf16 bf16x8 __attribute__((ext_vector_type(8)));
typedef __bf16 bf16x4 __attribute__((ext_vector_type(4)));
typedef float  f32x4  __attribute__((ext_vector_type(4)));

typedef void as1_void __attribute__((address_space(1)));
typedef void as3_void __attribute__((address_space(3)));

__device__ __forceinline__ void gload_lds16(const void* g, void* l) {
  __builtin_amdgcn_global_load_lds((as1_void*)g, (as3_void*)l, 16, 0, 0);
}

__device__ __forceinline__ uint32_t lds_addr32(const void* p) {
  return (uint32_t)(uintptr_t)(as3_void*)p;
}

// compiler-invisible LDS read (R4: breaks backend's conservative vmcnt drains)
__device__ __forceinline__ bf16x8 dsr128(uint32_t addr) {
  bf16x8 v;
  asm volatile("ds_read_b128 %0, %1" : "=v"(v) : "v"(addr));
  return v;
}

#define FENCE asm volatile("" ::: "memory")
#define BAR() do { FENCE; __builtin_amdgcn_s_barrier(); FENCE; } while (0)
#define LGKM0_FENCE() do { \
  asm volatile("s_waitcnt lgkmcnt(0)" ::: "memory"); \
  __builtin_amdgcn_sched_barrier(0); \
} while (0)

// ---------------- embedding + positional encoding ----------------
__global__ __launch_bounds__(256) void embed_kernel(const int* __restrict__ x,
    const float* __restrict__ emb, float* __restrict__ h) {
  int row = blockIdx.x;
  int s = row & (SEQ - 1);
  int d = threadIdx.x * 4;
  const float* e = emb + (size_t)x[row] * DM + d;
  float4 v = *(const float4*)e;
  float vin[4] = {v.x, v.y, v.z, v.w};
  float out[4];
#pragma unroll
  for (int j = 0; j < 4; ++j) {
    int dd = d + j;
    int i = dd >> 1;
    float freq = expf(-0.017988946039016376f * (float)i);
    float ang = (float)s * freq;
    float pe = (dd & 1) ? cosf(ang) : sinf(ang);
    out[j] = vin[j] + pe;
  }
  *(float4*)(h + (size_t)row * DM + d) = make_float4(out[0], out[1], out[2], out[3]);
}

// ---------------- layernorm (f32 in -> bf16 out) ----------------
__global__ __launch_bounds__(256) void ln_kernel(const float* __restrict__ x,
    const float* __restrict__ g, const float* __restrict__ b, bf16_t* __restrict__ out) {
  int row = blockIdx.x;
  int tid = threadIdx.x, lane = tid & 63, wave = tid >> 6;
  const float* xr = x + (size_t)row * DM;
  float4 v = ((const float4*)xr)[tid];
  float s1 = v.x + v.y + v.z + v.w;
  float s2 = v.x * v.x + v.y * v.y + v.z * v.z + v.w * v.w;
#pragma unroll
  for (int d = 1; d < 64; d <<= 1) { s1 += __shfl_xor(s1, d); s2 += __shfl_xor(s2, d); }
  __shared__ float red[8];
  if (lane == 0) { red[wave] = s1; red[4 + wave] = s2; }
  __syncthreads();
  s1 = red[0] + red[1] + red[2] + red[3];
  s2 = red[4] + red[5] + red[6] + red[7];
  float mu = s1 * (1.0f / DM);
  float var = s2 * (1.0f / DM) - mu * mu;
  float rs = rsqrtf(var + 1e-5f);
  float4 gv = ((const float4*)g)[tid];
  float4 bv = ((const float4*)b)[tid];
  bf16x4 o;
  o[0] = (bf16_t)((v.x - mu) * rs * gv.x + bv.x);
  o[1] = (bf16_t)((v.y - mu) * rs * gv.y + bv.y);
  o[2] = (bf16_t)((v.z - mu) * rs * gv.z + bv.z);
  o[3] = (bf16_t)((v.w - mu) * rs * gv.w + bv.w);
  *(bf16x4*)(out + (size_t)row * DM + tid * 4) = o;
}

// ------------- transpose + cast: f32 [K][N] -> bf16 [Npad][K] (head only) -------------
__global__ __launch_bounds__(256) void transpose_cast_kernel(const float* __restrict__ in,
    bf16_t* __restrict__ out, int K, int N, int Npad) {
  __shared__ float tile[32][33];
  int n0 = blockIdx.x * 32, k0 = blockIdx.y * 32;
  int tx = threadIdx.x & 31, ty = threadIdx.x >> 5;
#pragma unroll
  for (int kk = ty; kk < 32; kk += 8) {
    int n = n0 + tx;
    tile[kk][tx] = (n < N) ? in[(size_t)(k0 + kk) * N + n] : 0.f;
  }
  __syncthreads();
#pragma unroll
  for (int nn = ty; nn < 32; nn += 8) {
    out[(size_t)(n0 + nn) * K + k0 + tx] = (bf16_t)tile[tx][nn];
  }
}

// ------------- fused per-layer weight transpose (one launch) -------------
__global__ __launch_bounds__(256) void wtrans_kernel(
    const float* __restrict__ wq, const float* __restrict__ wk,
    const float* __restrict__ wv, const float* __restrict__ wo,
    const float* __restrict__ w1, const float* __restrict__ w2,
    bf16_t* __restrict__ qkvT, bf16_t* __restrict__ woT,
    bf16_t* __restrict__ w1T, bf16_t* __restrict__ w2T) {
  int id = blockIdx.x;
  const float* src; bf16_t* dst; int K, N, tk, tn;
  if (id < 4096) {
    int m = id >> 10, tile_i = id & 1023;
    tk = tile_i >> 5; tn = tile_i & 31; K = 1024; N = 1024;
    src = (m == 0) ? wq : (m == 1) ? wk : (m == 2) ? wv : wo;
    dst = (m < 3) ? qkvT + (size_t)m * DM * DM : woT;
  } else if (id < 8192) {
    int tile_i = id - 4096;
    tk = tile_i >> 7; tn = tile_i & 127; K = 1024; N = 4096;
    src = w1; dst = w1T;
  } else {
    int tile_i = id - 8192;
    tk = tile_i >> 5; tn = tile_i & 31; K = 4096; N = 1024;
    src = w2; dst = w2T;
  }
  __shared__ float tile[32][33];
  int n0 = tn * 32, k0 = tk * 32;
  int tx = threadIdx.x & 31, ty = threadIdx.x >> 5;
#pragma unroll
  for (int kk = ty; kk < 32; kk += 8)
    tile[kk][tx] = src[(size_t)(k0 + kk) * N + n0 + tx];
  __syncthreads();
#pragma unroll
  for (int nn = ty; nn < 32; nn += 8)
    dst[(size_t)(n0 + nn) * K + k0 + tx] = (bf16_t)tile[tx][nn];
}

// ------------- V transpose: qkv V slice -> vT [b][h][dk][S] (bf16) -------------
__global__ __launch_bounds__(256) void vtrans_kernel(const bf16_t* __restrict__ qkv,
    bf16_t* __restrict__ vT) {
  int sb = blockIdx.x, hh = blockIdx.y, bb = blockIdx.z;
  __shared__ bf16_t t[64][72];   // +8 pad
  int tid = threadIdx.x;
  const bf16_t* src = qkv + ((size_t)bb * SEQ + sb * 64) * (3 * DM) + 2 * DM + hh * DKH;
#pragma unroll
  for (int c = 0; c < 2; ++c) {
    int u = c * 256 + tid;
    int s = u >> 3, d8 = u & 7;
    *(bf16x8*)&t[s][d8 * 8] = *(const bf16x8*)(src + (size_t)s * (3 * DM) + d8 * 8);
  }
  __syncthreads();
  bf16_t* dst = vT + ((size_t)(bb * NH + hh) * DKH) * SEQ + sb * 64;
#pragma unroll
  for (int c = 0; c < 2; ++c) {
    int u = c * 256 + tid;
    int dk = u >> 3, s8 = u & 7;
    bf16x8 v;
#pragma unroll
    for (int j = 0; j < 8; ++j) v[j] = t[s8 * 8 + j][dk];
    *(bf16x8*)(dst + (size_t)dk * SEQ + s8 * 8) = v;
  }
}

// ---------------- gemm128-BK64: asm-dsr pipeline, 64 KB LDS dbuf (wo/w2) [R8] ----------------
__global__ __launch_bounds__(256, 2) void gemm128_kernel(
    const bf16_t* __restrict__ A, const bf16_t* __restrict__ Bt, int K,
    const float* __restrict__ bias, const float* __restrict__ Rsd,
    float* Cf, bf16_t* Cb, int ldc, int Nvalid, int relu, int gridM, int gridN) {
  __shared__ __align__(16) bf16_t lds[32768];   // 64 KB

  int nwg = gridM * gridN;
  int orig = blockIdx.x;
  int q = nwg >> 3, rr = nwg & 7;
  int xcd = orig & 7, idx = orig >> 3;
  int swz = (xcd < rr ? xcd * (q + 1) : rr * (q + 1) + (xcd - rr) * q) + idx;
  int bm = swz % gridM, bn = swz / gridM;
  int m0 = bm * 128, n0 = bn * 128;

  int tid = threadIdx.x, lane = tid & 63, wave = tid >> 6;
  int g = lane >> 4, r = lane & 15;
  int wr = wave >> 1, wc = wave & 1;

  f32x4 zero = {0.f, 0.f, 0.f, 0.f};
  f32x4 acc[4][4];
#pragma unroll
  for (int i = 0; i < 4; ++i)
#pragma unroll
    for (int j = 0; j < 4; ++j) acc[i][j] = zero;

  const bf16_t* Abase = A + (size_t)m0 * K;
  const bf16_t* Bbase = Bt + (size_t)n0 * K;
  int NT = K >> 6;

  uint32_t L0 = lds_addr32(lds);
  uint32_t aF = L0 + (uint32_t)((g * 128 + wr * 64 + r) * 16);
  uint32_t bF = L0 + 32768u + (uint32_t)((g * 128 + wc * 64 + r) * 16);

  auto stage = [&](int t) {
    int b = t & 1, k0 = t << 6;
    bf16_t* dA = lds + (size_t)b * 8192;
    bf16_t* dB = lds + 16384 + (size_t)b * 8192;
#pragma unroll
    for (int j = 0; j < 4; ++j) {
      int u = j * 256 + tid;
      int row = u & 127, k8 = u >> 7;
      gload_lds16(Abase + (size_t)row * K + k0 + k8 * 8, dA + (j * 256 + wave * 64) * 8);
    }
#pragma unroll
    for (int j = 0; j < 4; ++j) {
      int u = j * 256 + tid;
      int row = u & 127, k8 = u >> 7;
      gload_lds16(Bbase + (size_t)row * K + k0 + k8 * 8, dB + (j * 256 + wave * 64) * 8);
    }
  };

  stage(0);
  if (NT > 1) {
    stage(1);
    asm volatile("s_waitcnt vmcnt(8)" ::: "memory");
  } else {
    asm volatile("s_waitcnt vmcnt(0)" ::: "memory");
  }
  BAR();

  for (int t = 0; t < NT; ++t) {
    uint32_t boff = (uint32_t)((t & 1) << 14);
    bf16x8 af[4][2], bfr[4][2];
#pragma unroll
    for (int mr = 0; mr < 4; ++mr)
#pragma unroll
      for (int kk = 0; kk < 2; ++kk)
        af[mr][kk] = dsr128(aF + boff + (uint32_t)(kk * 8192 + mr * 256));
#pragma unroll
    for (int nr = 0; nr < 4; ++nr)
#pragma unroll
      for (int kk = 0; kk < 2; ++kk)
        bfr[nr][kk] = dsr128(bF + boff + (uint32_t)(kk * 8192 + nr * 256));
    LGKM0_FENCE();
    BAR();
    if (t + 2 < NT) stage(t + 2);
    __builtin_amdgcn_s_setprio(1);
#pragma unroll
    for (int mr = 0; mr < 4; ++mr)
#pragma unroll
      for (int nr = 0; nr < 4; ++nr) {
        acc[mr][nr] = __builtin_amdgcn_mfma_f32_16x16x32_bf16(af[mr][0], bfr[nr][0], acc[mr][nr], 0, 0, 0);
        acc[mr][nr] = __builtin_amdgcn_mfma_f32_16x16x32_bf16(af[mr][1], bfr[nr][1], acc[mr][nr], 0, 0, 0);
      }
    __builtin_amdgcn_s_setprio(0);
    __builtin_amdgcn_sched_barrier(0);
    if (t + 2 < NT) {
      asm volatile("s_waitcnt vmcnt(8)" ::: "memory");
    } else {
      asm volatile("s_waitcnt vmcnt(0)" ::: "memory");
    }
    BAR();
  }

#pragma unroll
  for (int mr = 0; mr < 4; ++mr) {
    int row = m0 + wr * 64 + mr * 16 + g * 4;
#pragma unroll
    for (int nr = 0; nr < 4; ++nr) {
      int col = n0 + wc * 64 + nr * 16 + r;
      if (col < Nvalid) {
        float bval = bias ? bias[col] : 0.f;
#pragma unroll
        for (int i = 0; i < 4; ++i) {
          float vv = acc[mr][nr][i] + bval;
          if (relu) vv = fmaxf(vv, 0.f);
          size_t idxo = (size_t)(row + i) * ldc + col;
          if (Rsd) vv += Rsd[idxo];
          if (Cf) Cf[idxo] = vv;
          if (Cb) Cb[idxo] = (bf16_t)vv;
        }
      }
    }
  }
}

// ---------------- gemm256: 8-phase, asm ds_reads (head/qkv/ffn1) [R8, best measured] ----------------
__global__ __launch_bounds__(512, 2) void gemm256_kernel(
    const bf16_t* __restrict__ A, const bf16_t* __restrict__ Bt, int K,
    const float* __restrict__ bias, float* Cf, bf16_t* Cb,
    int ldc, int Nvalid, int relu, int gridM, int gridN) {
  __shared__ __align__(16) bf16_t lds[65536];   // 128 KB

  int nwg = gridM * gridN;
  int orig = blockIdx.x;
  int q = nwg >> 3, rr = nwg & 7;
  int xcd = orig & 7, idx = orig >> 3;
  int swz = (xcd < rr ? xcd * (q + 1) : rr * (q + 1) + (xcd - rr) * q) + idx;
  int bm = swz % gridM, bn = swz / gridM;
  int m0 = bm * 256, n0 = bn * 256;

  int tid = threadIdx.x, lane = tid & 63, wave = tid >> 6;
  int g = lane >> 4, r = lane & 15;
  int wr = wave >> 2, wc = wave & 3;   // 2M x 4N

  f32x4 zero = {0.f, 0.f, 0.f, 0.f};
  f32x4 acc[8][4];
#pragma unroll
  for (int i = 0; i < 8; ++i)
#pragma unroll
    for (int j = 0; j < 4; ++j) acc[i][j] = zero;

  const bf16_t* Ab = A + (size_t)m0 * K;
  const bf16_t* Bb = Bt + (size_t)n0 * K;
  int NT = K >> 6;

  uint32_t L0 = lds_addr32(lds);
  uint32_t laneOff = (uint32_t)(g * 2048 + r * 16);
  uint32_t aBase0 = L0 + ((uint32_t)wr << 14) + laneOff;
  uint32_t bBase0 = L0 + 65536u + ((uint32_t)(wc >> 1) << 14) + laneOff
                  + (uint32_t)((wc & 1) * 1024);

  auto stageA = [&](int t, int hh) {
    int b = t & 1, k0 = t << 6;
    const bf16_t* src = Ab + (size_t)(hh * 128) * K + k0;
    bf16_t* dst = lds + (size_t)(b * 2 + hh) * 8192;
#pragma unroll
    for (int j = 0; j < 2; ++j) {
      int u = j * 512 + tid;
      gload_lds16(src + (size_t)(u & 127) * K + (u >> 7) * 8, dst + (j * 512 + wave * 64) * 8);
    }
  };
  auto stageB = [&](int t, int hh) {
    int b = t & 1, k0 = t << 6;
    const bf16_t* src = Bb + (size_t)(hh * 128) * K + k0;
    bf16_t* dst = lds + 32768 + (size_t)(b * 2 + hh) * 8192;
#pragma unroll
    for (int j = 0; j < 2; ++j) {
      int u = j * 512 + tid;
      gload_lds16(src + (size_t)(u & 127) * K + (u >> 7) * 8, dst + (j * 512 + wave * 64) * 8);
    }
  };

  stageB(0, 0); stageB(0, 1); stageA(0, 0); stageA(0, 1);
  if (NT > 1) {
    stageB(1, 0); stageB(1, 1);
    asm volatile("s_waitcnt vmcnt(4)" ::: "memory");
  } else {
    asm volatile("s_waitcnt vmcnt(0)" ::: "memory");
  }
  BAR();

  for (int t = 0; t < NT; ++t) {
    uint32_t bsel = (uint32_t)((t & 1) << 15);
    uint32_t Aaddr = aBase0 + bsel;
    uint32_t Baddr = bBase0 + bsel;

    bf16x8 a0[4][2], a1[4][2], b01[2][2], b23[2][2];

#pragma unroll
    for (int mi = 0; mi < 4; ++mi)
#pragma unroll
      for (int kk = 0; kk < 2; ++kk)
        a0[mi][kk] = dsr128(Aaddr + (uint32_t)(kk * 8192 + mi * 256));
#pragma unroll
    for (int ni = 0; ni < 2; ++ni)
#pragma unroll
      for (int kk = 0; kk < 2; ++kk)
        b01[ni][kk] = dsr128(Baddr + (uint32_t)(kk * 8192 + ni * 256));
    if (t + 1 < NT) stageA(t + 1, 0);
    BAR();
    LGKM0_FENCE();
    __builtin_amdgcn_s_setprio(1);
#pragma unroll
    for (int mi = 0; mi < 4; ++mi)
#pragma unroll
      for (int ni = 0; ni < 2; ++ni)
#pragma unroll
        for (int kk = 0; kk < 2; ++kk)
          acc[mi][ni] = __builtin_amdgcn_mfma_f32_16x16x32_bf16(a0[mi][kk], b01[ni][kk], acc[mi][ni], 0, 0, 0);
    __builtin_amdgcn_s_setprio(0);
    __builtin_amdgcn_sched_barrier(0);
    BAR();

#pragma unroll
    for (int ni = 0; ni < 2; ++ni)
#pragma unroll
      for (int kk = 0; kk < 2; ++kk)
        b23[ni][kk] = dsr128(Baddr + (uint32_t)(kk * 8192 + (ni + 2) * 256));
    if (t + 1 < NT) stageA(t + 1, 1);
    BAR();
    LGKM0_FENCE();
    __builtin_amdgcn_s_setprio(1);
#pragma unroll
    for (int mi = 0; mi < 4; ++mi)
#pragma unroll
      for (int ni = 0; ni < 2; ++ni)
#pragma unroll
        for (int kk = 0; kk < 2; ++kk)
          acc[mi][ni + 2] = __builtin_amdgcn_mfma_f32_16x16x32_bf16(a0[mi][kk], b23[ni][kk], acc[mi][ni + 2], 0, 0, 0);
    __builtin_amdgcn_s_setprio(0);
    __builtin_amdgcn_sched_barrier(0);
    BAR();

#pragma unroll
    for (int mi = 0; mi < 4; ++mi)
#pragma unroll
      for (int kk = 0; kk < 2; ++kk)
        a1[mi][kk] = dsr128(Aaddr + (uint32_t)(kk * 8192 + (mi + 4) * 256));
    if (t + 2 < NT) stageB(t + 2, 0);
    BAR();
    LGKM0_FENCE();
    __builtin_amdgcn_s_setprio(1);
#pragma unroll
    for (int mi = 0; mi < 4; ++mi)
#pragma unroll
      for (int ni = 0; ni < 2; ++ni)
#pragma unroll
        for (int kk = 0; kk < 2; ++kk)
          acc[mi + 4][ni] = __builtin_amdgcn_mfma_f32_16x16x32_bf16(a1[mi][kk], b01[ni][kk], acc[mi + 4][ni], 0, 0, 0);
    __builtin_amdgcn_s_setprio(0);
    __builtin_amdgcn_sched_barrier(0);
    BAR();

    if (t + 2 < NT) stageB(t + 2, 1);
    __builtin_amdgcn_sched_barrier(0);
    __builtin_amdgcn_s_setprio(1);
#pragma unroll
    for (int mi = 0; mi < 4; ++mi)
#pragma unroll
      for (int ni = 0; ni < 2; ++ni)
#pragma unroll
        for (int kk = 0; kk < 2; ++kk)
          acc[mi + 4][ni + 2] = __builtin_amdgcn_mfma_f32_16x16x32_bf16(a1[mi][kk], b23[ni][kk], acc[mi + 4][ni + 2], 0, 0, 0);
    __builtin_amdgcn_s_setprio(0);
    __builtin_amdgcn_sched_barrier(0);
    if (t + 2 < NT) {
      asm volatile("s_waitcnt vmcnt(4)" ::: "memory");
    } else {
      asm volatile("s_waitcnt vmcnt(0)" ::: "memory");
    }
    BAR();
  }

#pragma unroll
  for (int mi = 0; mi < 8; ++mi) {
    int row = m0 + wr * 128 + mi * 16 + g * 4;
#pragma unroll
    for (int ni = 0; ni < 4; ++ni) {
      int col = n0 + wc * 64 + ni * 16 + r;
      if (col < Nvalid) {
        float bval = bias ? bias[col] : 0.f;
#pragma unroll
        for (int i = 0; i < 4; ++i) {
          float vv = acc[mi][ni][i] + bval;
          if (relu) vv = fmaxf(vv, 0.f);
          size_t idxo = (size_t)(row + i) * ldc + col;
          if (Cf) Cf[idxo] = vv;
          if (Cb) Cb[idxo] = (bf16_t)vv;
        }
      }
    }
  }
}

// ---------------- flash attention: async K/V pipeline + T13 defer-max ----------------
__global__ __launch_bounds__(512, 4) void attn_kernel(const bf16_t* __restrict__ Qg,
    const bf16_t* __restrict__ Kg, const bf16_t* __restrict__ vT, bf16_t* __restrict__ Og,
    int ldq) {
  int bq = (int)gridDim.x - 1 - (int)blockIdx.x;
  int hh = blockIdx.y, bb = blockIdx.z;
  int tid = threadIdx.x, lane = tid & 63, wave = tid >> 6;
  int g = lane >> 4, r = lane & 15;
  __shared__ __align__(16) bf16_t Kl[2][4096];
  __shared__ __align__(16) bf16_t Vl[2][4096];
  __shared__ __align__(16) bf16_t Pl[8][1024];

  size_t base = (size_t)bb * SEQ * ldq + hh * DKH;
  size_t vbase = ((size_t)(bb * NH + hh)) * DKH * SEQ;
  size_t baseO = (size_t)bb * SEQ * DM + hh * DKH;
  int q0 = bq * 128 + wave * 16;
  const bf16_t* qrowp = Qg + base + (size_t)(q0 + r) * ldq;
  bf16x8 qf0 = *(const bf16x8*)(qrowp + g * 8);
  bf16x8 qf1 = *(const bf16x8*)(qrowp + 32 + g * 8);
#pragma unroll
  for (int j = 0; j < 8; ++j) {
    qf0[j] = (bf16_t)((float)qf0[j] * 0.125f);
    qf1[j] = (bf16_t)((float)qf1[j] * 0.125f);
  }

  uint32_t KlA = lds_addr32(&Kl[0][0]);
  uint32_t VlA = lds_addr32(&Vl[0][0]);
  int slot0 = g ^ (r & 7), slot1 = (4 + g) ^ (r & 7);

  f32x4 zero = {0.f, 0.f, 0.f, 0.f};
  f32x4 accO[4];
#pragma unroll
  for (int dt = 0; dt < 4; ++dt) accO[dt] = zero;
  float m_i[4], l_i[4];
#pragma unroll
  for (int i = 0; i < 4; ++i) { m_i[i] = -1e30f; l_i[i] = 0.f; }

  int skv = tid >> 3, kslot = tid & 7, kdk8 = kslot ^ (skv & 7);
  int sdk = tid >> 3, vslot = tid & 7, vkv8 = vslot ^ (sdk & 7);
  const bf16_t* ksrc0 = Kg + base + (size_t)skv * ldq + kdk8 * 8;
  const bf16_t* vsrc0 = vT + vbase + (size_t)sdk * SEQ + vkv8 * 8;

  auto stage = [&](int kb) {
    int c = kb & 1;
    gload_lds16(ksrc0 + (size_t)(kb * 64) * ldq, &Kl[c][(wave * 64) * 8]);
    gload_lds16(vsrc0 + kb * 64, &Vl[c][(wave * 64) * 8]);
  };

  int nkb = 2 * bq + 2;
  stage(0); stage(1);
  asm volatile("s_waitcnt vmcnt(2)" ::: "memory");
  BAR();

  for (int kb = 0; kb < nkb; ++kb) {
    uint32_t koff = KlA + (uint32_t)((kb & 1) << 13);
    uint32_t voff = VlA + (uint32_t)((kb & 1) << 13);

    bf16x8 kf[4][2];
#pragma unroll
    for (int ct = 0; ct < 4; ++ct) {
      int kvrow = ct * 16 + r;
      kf[ct][0] = dsr128(koff + (uint32_t)((kvrow * 8 + slot0) * 16));
      kf[ct][1] = dsr128(koff + (uint32_t)((kvrow * 8 + slot1) * 16));
    }
    LGKM0_FENCE();
    f32x4 sc[4];
#pragma unroll
    for (int ct = 0; ct < 4; ++ct) {
      f32x4 s = zero;
      s = __builtin_amdgcn_mfma_f32_16x16x32_bf16(qf0, kf[ct][0], s, 0, 0, 0);
      s = __builtin_amdgcn_mfma_f32_16x16x32_bf16(qf1, kf[ct][1], s, 0, 0, 0);
      sc[ct] = s;
    }

    // ---- tile max per row (pure tile max, 16-lane reduce) ----
    bool full = (kb * 64 + 63) <= q0;
    float tmx[4];
#pragma unroll
    for (int i = 0; i < 4; ++i) {
      float mx = -1e30f;
      if (full) {
#pragma unroll
        for (int ct = 0; ct < 4; ++ct) mx = fmaxf(mx, sc[ct][i]);
      } else {
        int qglob = q0 + g * 4 + i;
#pragma unroll
        for (int ct = 0; ct < 4; ++ct) {
          int kglob = kb * 64 + ct * 16 + r;
          float s = (kglob <= qglob) ? sc[ct][i] : -1e30f;
          sc[ct][i] = s;
          mx = fmaxf(mx, s);
        }
      }
#pragma unroll
      for (int d = 1; d < 16; d <<= 1) mx = fmaxf(mx, __shfl_xor(mx, d));
      tmx[i] = mx;
    }

    // ---- T13 defer-max: skip rescale if tile max within 8 of running max ----
    bool skip = __all(tmx[0] <= m_i[0] + 8.f && tmx[1] <= m_i[1] + 8.f &&
                      tmx[2] <= m_i[2] + 8.f && tmx[3] <= m_i[3] + 8.f);
#pragma unroll
    for (int i = 0; i < 4; ++i) {
      if (!skip) {
        float mnew = fmaxf(m_i[i], tmx[i]);
        float scl = __expf(m_i[i] - mnew);
        l_i[i] *= scl;
        m_i[i] = mnew;
#pragma unroll
        for (int dt = 0; dt < 4; ++dt) accO[dt][i] *= scl;
      }
      float rsum = 0.f;
#pragma unroll
      for (int ct = 0; ct < 4; ++ct) {
        float p = __expf(sc[ct][i] - m_i[i]);   // bounded by e^8 under skip
        sc[ct][i] = p;
        rsum += p;
      }
#pragma unroll
      for (int d = 1; d < 16; d <<= 1) rsum += __shfl_xor(rsum, d);
      l_i[i] += rsum;
    }

#pragma unroll
    for (int ct = 0; ct < 4; ++ct) {
      int kcol = ct * 16 + r;
#pragma unroll
      for (int i = 0; i < 4; ++i)
        Pl[wave][((kcol >> 3) * 16 + g * 4 + i) * 8 + (kcol & 7)] = (bf16_t)sc[ct][i];
    }
    bf16x8 pa0 = *(const bf16x8*)&Pl[wave][((0 + g) * 16 + r) * 8];
    bf16x8 pa1 = *(const bf16x8*)&Pl[wave][((4 + g) * 16 + r) * 8];

    bf16x8 vb[4][2];
#pragma unroll
    for (int dt = 0; dt < 4; ++dt) {
      int dkrow = dt * 16 + r;
      vb[dt][0] = dsr128(voff + (uint32_t)((dkrow * 8 + slot0) * 16));
      vb[dt][1] = dsr128(voff + (uint32_t)((dkrow * 8 + slot1) * 16));
    }
    LGKM0_FENCE();
#pragma unroll
    for (int dt = 0; dt < 4; ++dt) {
      accO[dt] = __builtin_amdgcn_mfma_f32_16x16x32_bf16(pa0, vb[dt][0], accO[dt], 0, 0, 0);
      accO[dt] = __builtin_amdgcn_mfma_f32_16x16x32_bf16(pa1, vb[dt][1], accO[dt], 0, 0, 0);
    }

    BAR();
    if (kb + 2 < nkb) {
      stage(kb + 2);
      asm volatile("s_waitcnt vmcnt(2)" ::: "memory");
    } else {
      asm volatile("s_waitcnt vmcnt(0)" ::: "memory");
    }
    BAR();
  }

#pragma unroll
  for (int dt = 0; dt < 4; ++dt)
#pragma unroll
    for (int i = 0; i < 4; ++i) {
      int rowq = q0 + g * 4 + i;
      Og[baseO + (size_t)rowq * DM + dt * 16 + r] = (bf16_t)(accO[dt][i] / l_i[i]);
    }
}

// ---------------- launcher (R8 routing: best measured) ----------------
static inline void launch_gemm256(const bf16_t* A, const bf16_t* Bt, int K,
    const float* bias, float* Cf, bf16_t* Cb, int ldc, int Nvalid, int relu,
    int M, int Npad, hipStream_t stream) {
  int gridM = M / 256, gridN = Npad / 256;
  gemm256_kernel<<<dim3(gridM * gridN), 512, 0, stream>>>(
      A, Bt, K, bias, Cf, Cb, ldc, Nvalid, relu, gridM, gridN);
}

static inline void launch_gemm128(const bf16_t* A, const bf16_t* Bt, int K,
    const float* bias, const float* Rsd, float* Cf, bf16_t* Cb,
    int ldc, int Nvalid, int relu, int M, int Npad, hipStream_t stream) {
  int gridM = M / 128, gridN = Npad / 128;
  gemm128_kernel<<<dim3(gridM * gridN), 256, 0, stream>>>(
      A, Bt, K, bias, Rsd, Cf, Cb, ldc, Nvalid, relu, gridM, gridN);
}

extern "C" void kernel_launch(void* const* d_in, const int* in_sizes, int n_in,
                              void* d_out, int out_size, void* d_ws, size_t ws_size,
                              hipStream_t stream) {
  const int*   x      = (const int*)d_in[0];
  const float* emb    = (const float*)d_in[1];
  const float* ln1_g  = (const float*)d_in[2];
  const float* ln1_b  = (const float*)d_in[3];
  const float* wq     = (const float*)d_in[4];
  const float* wk     = (const float*)d_in[5];
  const float* wv     = (const float*)d_in[6];
  const float* wo     = (const float*)d_in[7];
  const float* ln2_g  = (const float*)d_in[8];
  const float* ln2_b  = (const float*)d_in[9];
  const float* w1     = (const float*)d_in[10];
  const float* b1     = (const float*)d_in[11];
  const float* w2     = (const float*)d_in[12];
  const float* b2     = (const float*)d_in[13];
  const float* lnf_g  = (const float*)d_in[14];
  const float* lnf_b  = (const float*)d_in[15];
  const float* head_w = (const float*)d_in[16];
  const float* head_b = (const float*)d_in[17];
  float* out = (float*)d_out;

  char* ws = (char*)d_ws;
  size_t off = 0;
  auto alloc = [&](size_t bytes) -> void* {
    void* p = ws + off;
    off += (bytes + 255) & ~(size_t)255;
    return p;
  };
  float*  h     = (float*)alloc((size_t)MROWS * DM * 4);
  bf16_t* hn    = (bf16_t*)alloc((size_t)MROWS * DM * 2);
  bf16_t* qkv   = (bf16_t*)alloc((size_t)MROWS * 3 * DM * 2);
  bf16_t* atb   = (bf16_t*)alloc((size_t)MROWS * DM * 2);
  bf16_t* ffn1  = (bf16_t*)alloc((size_t)MROWS * FF * 2);
  bf16_t* vTb   = (bf16_t*)alloc((size_t)BATCH * NH * DKH * SEQ * 2);
  bf16_t* headT = (bf16_t*)alloc((size_t)VPAD * DM * 2);
  bf16_t* wqkvT = headT;                                   // 3 x 1M
  bf16_t* woT   = headT + (size_t)3 * DM * DM;             // 1M
  bf16_t* w1T   = headT + (size_t)4 * DM * DM;             // 4M
  bf16_t* w2T   = headT + (size_t)4 * DM * DM + (size_t)DM * FF;  // 4M

  embed_kernel<<<MROWS, 256, 0, stream>>>(x, emb, h);

  for (int l = 0; l < NL; ++l) {
    ln_kernel<<<MROWS, 256, 0, stream>>>(h, ln1_g + l * DM, ln1_b + l * DM, hn);

    wtrans_kernel<<<12288, 256, 0, stream>>>(
        wq + (size_t)l * DM * DM, wk + (size_t)l * DM * DM, wv + (size_t)l * DM * DM,
        wo + (size_t)l * DM * DM, w1 + (size_t)l * DM * FF, w2 + (size_t)l * FF * DM,
        wqkvT, woT, w1T, w2T);

    launch_gemm256(hn, wqkvT, DM, nullptr, nullptr, qkv, 3 * DM, 3 * DM, 0,
                   MROWS, 3 * DM, stream);

    vtrans_kernel<<<dim3(SEQ / 64, NH, BATCH), 256, 0, stream>>>(qkv, vTb);
    attn_kernel<<<dim3(SEQ / 128, NH, BATCH), 512, 0, stream>>>(
        qkv, qkv + DM, vTb, atb, 3 * DM);

    launch_gemm128(atb, woT, DM, nullptr, h, h, nullptr, DM, DM, 0, MROWS, DM, stream);

    ln_kernel<<<MROWS, 256, 0, stream>>>(h, ln2_g + l * DM, ln2_b + l * DM, hn);

    launch_gemm256(hn, w1T, DM, b1 + (size_t)l * FF, nullptr, ffn1, FF, FF, 1,
                   MROWS, FF, stream);

    launch_gemm128(ffn1, w2T, FF, b2 + (size_t)l * DM, h, h, nullptr, DM, DM, 0,
                   MROWS, DM, stream);
  }

  ln_kernel<<<MROWS, 256, 0, stream>>>(h, lnf_g, lnf_b, hn);
  transpose_cast_kernel<<<dim3(VPAD / 32, DM / 32), 256, 0, stream>>>(
      head_w, headT, DM, VOCAB, VPAD);
  launch_gemm256(hn, headT, DM, head_b, out, nullptr, VOCAB, VOCAB, 0,
                 MROWS, VPAD, stream);
}